// Round 4
// baseline (322.479 us; speedup 1.0000x reference)
//
#include <hip/hip_runtime.h>
#include <stdint.h>
#include <stddef.h>

#define BDIM 4
#define QUE  128
#define VAL  128
#define DD   512
#define BQ   (BDIM*QUE)
#define BK   64
#define GRID 512
// gemm LDS: 8 slots of 8 f16 (16B) per row; true kseg c stored at slot (c + (r&7)) & 7

typedef float    f32x4 __attribute__((ext_vector_type(4)));
typedef _Float16 f16x8 __attribute__((ext_vector_type(8)));
typedef _Float16 f16x4 __attribute__((ext_vector_type(4)));

typedef const __attribute__((address_space(1))) void* gas_ptr;
typedef __attribute__((address_space(3))) void*       las_ptr;

__device__ __forceinline__ void async_copy16(const void* g, void* l) {
    __builtin_amdgcn_global_load_lds((gas_ptr)g, (las_ptr)l, 16, 0, 0);
}

// grid barrier: release-fence + device-scope arrive, AGENT-scope spin, acquire-fence.
// Safe: co-residency guaranteed (LDS 53KB -> 3/CU, regs<=128 -> 2/CU, 512 = 256*2).
__device__ __forceinline__ void gsync(unsigned* ctr) {
    __syncthreads();
    if (threadIdx.x == 0) {
        __threadfence();
        atomicAdd(ctr, 1u);
        while (__hip_atomic_load(ctr, __ATOMIC_RELAXED, __HIP_MEMORY_SCOPE_AGENT)
               < (unsigned)GRID)
            __builtin_amdgcn_s_sleep(2);
    }
    __syncthreads();
    __threadfence();   // acquire: subsequent loads see other XCDs' writes
}

#define MPAD 514   // meanLDS row stride (f16): 257 dwords == 1 mod 32 -> conflict-free
#define WPAD 130   // wLDS/BLDS row stride: 65 dwords == 1 mod 32

__global__ __launch_bounds__(512, 4) void mega_kernel(
    const float* __restrict__ qs1, const float* __restrict__ ks,
    const float* __restrict__ vs,  const int*   __restrict__ sgmask,
    const float* __restrict__ W1,  const float* __restrict__ b1,
    const float* __restrict__ Wse, const float* __restrict__ bse,
    const float* __restrict__ W2,  const float* __restrict__ b2,
    float* __restrict__ out,
    _Float16* __restrict__ W1T, _Float16* __restrict__ WseT,
    _Float16* __restrict__ vsT, float* __restrict__ s_part,
    float* __restrict__ msum,   _Float16* __restrict__ qH,
    _Float16* __restrict__ ksH, unsigned* __restrict__ bar)
{
    __shared__ char lds[53248] __attribute__((aligned(16)));
    const int tid = threadIdx.x;
    const int blk = blockIdx.x;

    // ================= phase P: prep (all 512 blocks) =================
    if (blk < 256) {
        // W1 tile (threads 0-255) and Wse tile (threads 256-511), 32x32 f32 transpose
        const int half = tid >> 8;
        const int t    = tid & 255;
        const float* src = half ? Wse : W1;
        _Float16*    dst = half ? WseT : W1T;
        float (*tl)[33] = (float(*)[33])(lds + half * 4224);
        const int a0 = (blk & 15) * 32;      // source-row tile
        const int b0 = (blk >> 4) * 32;      // source-col tile
        const int tx = t & 31, ty = t >> 5;  // ty 0..7
        #pragma unroll
        for (int r = 0; r < 4; ++r)
            tl[ty + r*8][tx] = src[(size_t)(a0 + ty + r*8) * DD + b0 + tx];
        __syncthreads();
        #pragma unroll
        for (int r = 0; r < 4; ++r) {
            int el = ty + r*8;
            dst[(size_t)(b0 + el) * DD + a0 + tx] = (_Float16)tl[tx][el];
        }
    } else {
        const int job = blk - 256;           // 0..255
        float (*tl)[33] = (float(*)[33])lds;
        const int bb = job >> 6;             // batch 0..3
        const int gx = (job >> 2) & 15;      // d tile
        const int vt = job & 3;              // v subtile
        const float* srcv = vs  + (size_t)bb * VAL * DD;
        _Float16*    dstv = vsT + (size_t)bb * DD * VAL;
        const int b0 = gx * 32, a0 = vt * 32;
        const int tx = tid & 31, ty = (tid >> 5) & 7;
        if (tid < 256) {                     // vs load into tile
            #pragma unroll
            for (int r = 0; r < 4; ++r)
                tl[ty + r*8][tx] = srcv[(size_t)(a0 + ty + r*8) * DD + b0 + tx];
        } else {                             // flat cast chunk 1: qs1 -> qH
            int idx = job * 256 + (tid - 256);           // 0..65535
            f32x4 w = *(const f32x4*)(qs1 + (size_t)idx * 4);
            f16x4 h; h[0]=(_Float16)w[0]; h[1]=(_Float16)w[1];
            h[2]=(_Float16)w[2]; h[3]=(_Float16)w[3];
            *(f16x4*)(qH + (size_t)idx * 4) = h;
        }
        __syncthreads();
        if (tid < 256) {                     // vs store transposed
            #pragma unroll
            for (int r = 0; r < 4; ++r) {
                int el = ty + r*8;
                dstv[(size_t)(b0 + el) * VAL + a0 + tx] = (_Float16)tl[tx][el];
            }
        } else {                             // flat cast chunk 2: ks -> ksH
            int idx = job * 256 + (tid - 256);
            f32x4 w = *(const f32x4*)(ks + (size_t)idx * 4);
            f16x4 h; h[0]=(_Float16)w[0]; h[1]=(_Float16)w[1];
            h[2]=(_Float16)w[2]; h[3]=(_Float16)w[3];
            *(f16x4*)(ksH + (size_t)idx * 4) = h;
        }
    }

    gsync(bar + 0);

    // ================= phase G: fused GEMM (r0 structure, gy looped) =================
    {
        _Float16* Ah = (_Float16*)lds;                       // 16 KB
        _Float16* Bh = (_Float16*)(lds + 16384);             // 32 KB
        float (*sred)[VAL]    = (float(*)[VAL])(lds + 49152);    // 2 KB
        float (*msumLDS)[256] = (float(*)[256])(lds + 51200);    // 2 KB

        const int bq   = blk;
        const int b    = bq >> 7;
        const int lane = tid & 63;
        const int wid  = tid >> 6;            // 0..7
        const int wm   = wid >> 2;            // 0..1
        const int wn   = wid & 3;             // 0..3
        const int quad = lane >> 4;
        const int lr   = lane & 15;

        // A staging addressing (gy-invariant)
        const int ar0 = tid >> 3;
        const int slt = tid & 7;
        const int ca0 = (slt - (ar0 & 7)) & 7;
        const _Float16* ksrow0 = ksH + ((size_t)b * VAL + ar0)      * DD + ca0 * 8;
        const _Float16* ksrow1 = ksH + ((size_t)b * VAL + 64 + ar0) * DD + ca0 * 8;
        const _Float16* qrow_g = qH  + (size_t)bq * DD + ca0 * 8;
        const int aoff0 = tid * 8;
        const int aoff1 = (512 + tid) * 8;

        int faoff[4], fboff[4];
        #pragma unroll
        for (int mt = 0; mt < 4; ++mt) {
            int row = wm * 64 + mt * 16 + lr;
            faoff[mt] = row * BK + (((quad + row) & 7) << 3);
        }
        #pragma unroll
        for (int nt = 0; nt < 4; ++nt) {
            int row = wn * 64 + nt * 16 + lr;
            fboff[nt] = row * BK + (((quad + row) & 7) << 3);
        }

        for (int gy = 0; gy < 2; ++gy) {
            __syncthreads();      // LDS safe to overwrite (prep / prev epilogue done)

            const _Float16* gB[4];
            int ldsBoff[4];
            #pragma unroll
            for (int j = 0; j < 4; ++j) {
                int chunk = j * 512 + tid;
                int row   = chunk >> 3;
                int c     = ((chunk & 7) - (row & 7)) & 7;
                gB[j] = W1T + (size_t)(gy * 256 + row) * DD + c * 8;
                ldsBoff[j] = (j * 512 + wid * 64) * 8;
            }

            f32x4 acc[4][4];
            #pragma unroll
            for (int i = 0; i < 4; ++i)
                #pragma unroll
                for (int j = 0; j < 4; ++j) acc[i][j] = (f32x4){0.f,0.f,0.f,0.f};

            f16x8 kv0 = *(const f16x8*)(ksrow0);
            f16x8 kv1 = *(const f16x8*)(ksrow1);
            f16x8 qv  = *(const f16x8*)(qrow_g);

            for (int i = 0; i < 8; ++i) {
                const int kk = i * BK;
                #pragma unroll
                for (int j = 0; j < 4; ++j)
                    async_copy16(gB[j] + kk, &Bh[ldsBoff[j]]);
                *(f16x8*)&Ah[aoff0] = kv0 * qv;
                *(f16x8*)&Ah[aoff1] = kv1 * qv;
                __syncthreads();              // barrier1: staging visible

                if (i < 7) {
                    kv0 = *(const f16x8*)(ksrow0 + kk + BK);
                    kv1 = *(const f16x8*)(ksrow1 + kk + BK);
                    qv  = *(const f16x8*)(qrow_g + kk + BK);
                }
                #pragma unroll
                for (int s = 0; s < 2; ++s) {
                    const int sx = s << 5;
                    f16x8 fa[4];
                    #pragma unroll
                    for (int mt = 0; mt < 4; ++mt)
                        fa[mt] = *(const f16x8*)&Ah[faoff[mt] ^ sx];
                    #pragma unroll
                    for (int nt = 0; nt < 4; ++nt) {
                        f16x8 fb = *(const f16x8*)&Bh[fboff[nt] ^ sx];
                        #pragma unroll
                        for (int mt = 0; mt < 4; ++mt)
                            acc[mt][nt] = __builtin_amdgcn_mfma_f32_16x16x32_f16(
                                fa[mt], fb, acc[mt][nt], 0, 0, 0);
                    }
                }
                __syncthreads();              // barrier2: frag reads done
            }

            // fused epilogue: C/D layout col=lr (e), row=quad*4+reg (v)
            float b1v[4], w2v[4];
            #pragma unroll
            for (int nt = 0; nt < 4; ++nt) {
                int col = gy*256 + wn*64 + nt*16 + lr;
                b1v[nt] = b1[col];
                w2v[nt] = W2[col];
            }
            float msm[4] = {0.f, 0.f, 0.f, 0.f};
            #pragma unroll
            for (int mt = 0; mt < 4; ++mt) {
                #pragma unroll
                for (int reg = 0; reg < 4; ++reg) {
                    int v = wm*64 + mt*16 + quad*4 + reg;
                    int masked = sgmask[b * VAL + v];
                    float sacc = 0.f;
                    #pragma unroll
                    for (int nt = 0; nt < 4; ++nt) {
                        float h = acc[mt][nt][reg] + b1v[nt];
                        h = fmaxf(h, 0.f);
                        sacc += h * w2v[nt];
                        if (!masked) msm[nt] += h;
                    }
                    sacc += __shfl_xor(sacc, 1);
                    sacc += __shfl_xor(sacc, 2);
                    sacc += __shfl_xor(sacc, 4);
                    sacc += __shfl_xor(sacc, 8);
                    if (lr == 0) sred[wn][v] = sacc;
                }
            }
            #pragma unroll
            for (int nt = 0; nt < 4; ++nt) {
                float m = msm[nt];
                m += __shfl_xor(m, 16);
                m += __shfl_xor(m, 32);
                if (lane < 16) msumLDS[wm][wn*64 + nt*16 + lr] = m;
            }
            __syncthreads();
            if (tid < 128) {
                s_part[((size_t)bq * 2 + gy) * VAL + tid] =
                    sred[0][tid] + sred[1][tid] + sred[2][tid] + sred[3][tid];
            } else if (tid >= 256 && tid < 384) {
                int c = tid - 256;
                msum[(size_t)bq * DD + gy*256 + c]       = msumLDS[0][c] + msumLDS[1][c];
            } else if (tid >= 384) {
                int c = tid - 384 + 128;
                msum[(size_t)bq * DD + gy*256 + c]       = msumLDS[0][c] + msumLDS[1][c];
            }
        }
    }

    gsync(bar + 1);

    // ================= phase F: softmax + gate/out GEMMs (blocks 0-255) =============
    if (blk < 256) {
        _Float16* meanLDS = (_Float16*)lds;               // 32*514*2 = 32896 B
        _Float16* wLDS    = (_Float16*)(lds + 32896);     // 32*130*2 =  8320 B
        _Float16* BLDS    = (_Float16*)(lds + 41216);     //            8320 B

        const bool act = tid < 256;
        const int q0   = (blk >> 4) * 32;
        const int d0   = (blk & 15) * 32;
        const int b    = q0 >> 7;
        const int lane = tid & 63;
        const int wid  = tid >> 6;                // 0..3 for active threads
        const int wm   = wid >> 1, wn = wid & 1;
        const int quad = lane >> 4;
        const int lr   = lane & 15;
        const int r    = (tid >> 3) & 31;
        const int sl   = tid & 7;

        const int a_off  = (wm*16 + lr) * MPAD + quad*8;
        const int b_off  = (wn*16 + lr) * WPAD + quad*8;
        const int st_off = r * WPAD + sl*16;

        if (act) {
            // ---- phase A: softmax over v (8 lanes/row) + mean ----
            const float b2v = b2[0];
            const int   bq  = q0 + r;
            const float* sp = s_part + (size_t)bq * 2 * VAL;
            float vals[16];
            int   msk[16];
            float smax = -3.4e38f;
            #pragma unroll
            for (int i4 = 0; i4 < 4; ++i4) {
                f32x4 s0 = *(const f32x4*)(sp + sl*16 + i4*4);
                f32x4 s1 = *(const f32x4*)(sp + VAL + sl*16 + i4*4);
                #pragma unroll
                for (int j = 0; j < 4; ++j) {
                    int idx = i4*4 + j;
                    int v   = sl*16 + idx;
                    float s = fmaxf(s0[j] + s1[j] + b2v, 0.f);
                    int m   = sgmask[b * VAL + v];
                    msk[idx] = m;
                    if (m) s = -1e9f;
                    vals[idx] = s;
                    smax = fmaxf(smax, s);
                }
            }
            smax = fmaxf(smax, __shfl_xor(smax, 1));
            smax = fmaxf(smax, __shfl_xor(smax, 2));
            smax = fmaxf(smax, __shfl_xor(smax, 4));
            float sume = 0.f, cnt = 0.f;
            #pragma unroll
            for (int i = 0; i < 16; ++i) {
                vals[i] = __expf(vals[i] - smax);
                sume += vals[i];
                cnt  += msk[i] ? 0.f : 1.f;
            }
            sume += __shfl_xor(sume, 1);  cnt += __shfl_xor(cnt, 1);
            sume += __shfl_xor(sume, 2);  cnt += __shfl_xor(cnt, 2);
            sume += __shfl_xor(sume, 4);  cnt += __shfl_xor(cnt, 4);
            const float invse = 1.f / sume;
            const float invd  = 1.f / cnt;
            f16x8 wv0, wv1;
            #pragma unroll
            for (int i = 0; i < 8; ++i) {
                wv0[i] = (_Float16)(vals[i]     * invse);
                wv1[i] = (_Float16)(vals[i + 8] * invse);
            }
            *(f16x8*)&wLDS[r * WPAD + sl*16]     = wv0;
            *(f16x8*)&wLDS[r * WPAD + sl*16 + 8] = wv1;
            const float* mrow = msum + (size_t)bq * DD;
            #pragma unroll
            for (int i = 0; i < 8; ++i) {
                int e = i*64 + sl*8;
                f32x4 m0 = *(const f32x4*)(mrow + e);
                f32x4 m1 = *(const f32x4*)(mrow + e + 4);
                f16x8 mh;
                #pragma unroll
                for (int c = 0; c < 4; ++c) {
                    mh[c]     = (_Float16)(m0[c] * invd);
                    mh[c + 4] = (_Float16)(m1[c] * invd);
                }
                *(f16x8*)&meanLDS[r * MPAD + e] = mh;
            }
        }
        __syncthreads();

        // ---- phase B: gate GEMM (K=512, 4 chunks of 128) ----
        f32x4 accg = (f32x4){0.f, 0.f, 0.f, 0.f};
        #pragma unroll
        for (int cc = 0; cc < 4; ++cc) {
            if (act) {
                const _Float16* wrow = WseT + (size_t)(d0 + r) * DD + cc*128 + sl*16;
                f16x8 bw0 = *(const f16x8*)(wrow);
                f16x8 bw1 = *(const f16x8*)(wrow + 8);
                *(f16x8*)&BLDS[st_off]     = bw0;
                *(f16x8*)&BLDS[st_off + 8] = bw1;
            }
            __syncthreads();
            if (act) {
                #pragma unroll
                for (int ksi = 0; ksi < 4; ++ksi) {
                    f16x8 fa = *(const f16x8*)&meanLDS[a_off + cc*128 + ksi*32];
                    f16x8 fb = *(const f16x8*)&BLDS[b_off + ksi*32];
                    accg = __builtin_amdgcn_mfma_f32_16x16x32_f16(fa, fb, accg, 0, 0, 0);
                }
            }
            __syncthreads();
        }

        // ---- phase C: out GEMM (K=128) ----
        if (act) {
            const _Float16* vrow = vsT + ((size_t)b * DD + d0 + r) * VAL + sl*16;
            f16x8 bv0 = *(const f16x8*)(vrow);
            f16x8 bv1 = *(const f16x8*)(vrow + 8);
            *(f16x8*)&BLDS[st_off]     = bv0;
            *(f16x8*)&BLDS[st_off + 8] = bv1;
        }
        __syncthreads();
        if (act) {
            f32x4 acco = (f32x4){0.f, 0.f, 0.f, 0.f};
            const int w_off = (wm*16 + lr) * WPAD + quad*8;
            #pragma unroll
            for (int ksi = 0; ksi < 4; ++ksi) {
                f16x8 fa = *(const f16x8*)&wLDS[w_off + ksi*32];
                f16x8 fb = *(const f16x8*)&BLDS[b_off + ksi*32];
                acco = __builtin_amdgcn_mfma_f32_16x16x32_f16(fa, fb, acco, 0, 0, 0);
            }
            // ---- phase D: epilogue ----
            const int d = d0 + wn*16 + lr;
            const float bsev = bse[d];
            #pragma unroll
            for (int reg = 0; reg < 4; ++reg) {
                int q = q0 + wm*16 + quad*4 + reg;
                float g = fmaxf(accg[reg] + bsev, 0.f);
                g = 1.f / (1.f + __expf(-g));
                out[(size_t)q * DD + d] = g * acco[reg];
            }
        }
    }
}

extern "C" void kernel_launch(void* const* d_in, const int* in_sizes, int n_in,
                              void* d_out, int out_size, void* d_ws, size_t ws_size,
                              hipStream_t stream) {
    (void)in_sizes; (void)n_in; (void)out_size; (void)ws_size;
    const float* qs1 = (const float*)d_in[0];
    const float* ks  = (const float*)d_in[2];
    const float* vs  = (const float*)d_in[3];
    const int*   sg  = (const int*)d_in[4];
    const float* W1  = (const float*)d_in[5];
    const float* b1  = (const float*)d_in[6];
    const float* Wse = (const float*)d_in[7];
    const float* bse = (const float*)d_in[8];
    const float* W2  = (const float*)d_in[9];
    const float* b2  = (const float*)d_in[10];
    float* out = (float*)d_out;

    char* ws = (char*)d_ws;
    _Float16* W1T    = (_Float16*)(ws);                        // 512 KB
    _Float16* WseT   = (_Float16*)(ws + (512 << 10));          // 512 KB
    _Float16* vsT    = (_Float16*)(ws + (1 << 20));            // 512 KB
    float*    s_part = (float*)(ws + (1536 << 10));            // 512 KB
    float*    msum   = (float*)(ws + (2 << 20));               // 1 MB
    _Float16* qH     = (_Float16*)(ws + (3 << 20));            // 512 KB
    _Float16* ksH    = (_Float16*)(ws + (3 << 20) + (512 << 10)); // 512 KB
    unsigned* bar    = (unsigned*)(ws + (4 << 20));            // 256 B barrier state

    hipMemsetAsync(bar, 0, 256, stream);
    mega_kernel<<<dim3(GRID), dim3(512), 0, stream>>>(
        qs1, ks, vs, sg, W1, b1, Wse, bse, W2, b2, out,
        W1T, WseT, vsT, s_part, msum, qH, ksH, bar);
}

// Round 5
// 126.040 us; speedup vs baseline: 2.5586x; 2.5586x over previous
//
#include <hip/hip_runtime.h>
#include <stdint.h>
#include <stddef.h>

#define BDIM 4
#define QUE  128
#define VAL  128
#define DD   512
#define BQ   (BDIM*QUE)
#define BK   64
// gemm LDS: 8 slots of 8 f16 (16B) per row; true kseg c stored at slot (c + (r&7)) & 7

typedef float    f32x4 __attribute__((ext_vector_type(4)));
typedef _Float16 f16x8 __attribute__((ext_vector_type(8)));
typedef _Float16 f16x4 __attribute__((ext_vector_type(4)));

typedef const __attribute__((address_space(1))) void* gas_ptr;
typedef __attribute__((address_space(3))) void*       las_ptr;

__device__ __forceinline__ void async_copy16(const void* g, void* l) {
    __builtin_amdgcn_global_load_lds((gas_ptr)g, (las_ptr)l, 16, 0, 0);
}

// ---------------- prep v2: uniform 1-tile jobs, balanced. grid (16, 52).
//  gy  0..15 : W1  32x32 transpose tile  -> W1T[e][d]
//  gy 16..31 : Wse 32x32 transpose tile  -> WseT[d][e]
//  gy 32..47 : vs  32x32 transpose tile  -> vsT[b][d][v]   (bb=(gy-32)>>2, vt=(gy-32)&3)
//  gy 48..51 : flat f32->f16 casts: 48,49 qs1->qH halves; 50,51 ks->ksH halves
__global__ __launch_bounds__(256) void prep_kernel(const float* __restrict__ W1,
                                                   _Float16* __restrict__ W1T,
                                                   const float* __restrict__ Wse,
                                                   _Float16* __restrict__ WseT,
                                                   const float* __restrict__ vs,
                                                   _Float16* __restrict__ vsT,
                                                   const float* __restrict__ qs1,
                                                   _Float16* __restrict__ qH,
                                                   const float* __restrict__ ks,
                                                   _Float16* __restrict__ ksH) {
    const int gx = blockIdx.x, gy = blockIdx.y;
    if (gy >= 48) {
        const float* src = (gy < 50) ? qs1 : ks;
        _Float16*    dst = (gy < 50) ? qH  : ksH;
        size_t base = ((size_t)(gy & 1) * 16 + gx) * 8192 + threadIdx.x * 4;
        #pragma unroll
        for (int i = 0; i < 8; ++i) {
            f32x4 w = *(const f32x4*)(src + base + (size_t)i * 1024);
            f16x4 h;
            h[0] = (_Float16)w[0]; h[1] = (_Float16)w[1];
            h[2] = (_Float16)w[2]; h[3] = (_Float16)w[3];
            *(f16x4*)(dst + base + (size_t)i * 1024) = h;
        }
        return;
    }
    __shared__ float tile[32][33];
    const int tx = threadIdx.x & 31;
    const int ty = threadIdx.x >> 5;      // 0..7
    const float* src;
    _Float16*    dst;
    int a0, b0, dstride;
    if (gy < 32) {
        src = (gy < 16) ? W1  : Wse;
        dst = (gy < 16) ? W1T : WseT;
        a0 = gx * 32;                     // source-row tile (d)
        b0 = (gy & 15) * 32;              // source-col tile (e)
        dstride = DD;
    } else {
        const int j  = gy - 32;
        const int bb = j >> 2;            // batch
        const int vt = j & 3;             // v subtile
        src = vs  + (size_t)bb * VAL * DD;
        dst = vsT + (size_t)bb * DD * VAL;
        a0 = vt * 32;                     // source-row tile (v)
        b0 = gx * 32;                     // source-col tile (d)
        dstride = VAL;
    }
    #pragma unroll
    for (int r = 0; r < 4; ++r)
        tile[ty + r*8][tx] = src[(size_t)(a0 + ty + r*8) * DD + b0 + tx];
    __syncthreads();
    #pragma unroll
    for (int r = 0; r < 4; ++r) {
        int el = ty + r*8;
        dst[(size_t)(b0 + el) * dstride + a0 + tx] = (_Float16)tile[tx][el];
    }
}

// ---------------- fused GEMM: h=relu((q*k)@W1+b1); emit s-partials + masked colsums
// grid (BQ, 2); block 512 = 8 waves as 2m x 4n of 64x64. Tile 128 rows x 256 e-cols.
// (r0 structure, verified 51.2us — DO NOT TOUCH)
__global__ __launch_bounds__(512, 4) void gemm_h_kernel(
    const _Float16* __restrict__ qH,    // [BQ][DD] fp16
    const _Float16* __restrict__ ksH,   // [B][VAL][DD] fp16
    const int*   __restrict__ sgmask,
    const _Float16* __restrict__ W1T,   // [e][d] fp16
    const float* __restrict__ b1,
    const float* __restrict__ W2,
    float* __restrict__ s_part,         // [BQ][2][VAL]
    float* __restrict__ meansum)        // [BQ][DD]
{
    __shared__ _Float16 Ah[128 * BK];     // x tile   [v][k]  16 KB
    __shared__ _Float16 Bh[256 * BK];     // W1T tile [e][k]  32 KB
    __shared__ float sred[4][VAL];
    __shared__ float msumLDS[2][256];

    const int tid  = threadIdx.x;
    const int bq   = blockIdx.x;
    const int gy   = blockIdx.y;          // e-half: cols [gy*256, gy*256+256)
    const int b    = bq >> 7;
    const int lane = tid & 63;
    const int wid  = tid >> 6;            // 0..7
    const int wm   = wid >> 2;            // 0..1 (rows wm*64)
    const int wn   = wid & 3;             // 0..3 (cols wn*64)
    const int quad = lane >> 4;
    const int lr   = lane & 15;

    f32x4 acc[4][4];
    #pragma unroll
    for (int i = 0; i < 4; ++i)
        #pragma unroll
        for (int j = 0; j < 4; ++j) acc[i][j] = (f32x4){0.f, 0.f, 0.f, 0.f};

    // ---- A staging: 2 chunks/thread (chunk = tid, tid+512); chunk -> row=c>>3, slot=c&7
    const int ar0 = tid >> 3;             // chunk tid   -> row 0..63
    const int slt = tid & 7;
    const int ca0 = (slt - (ar0 & 7)) & 7;   // true kseg; rows ar0 and ar0+64 share it
    const _Float16* ksrow0 = ksH + ((size_t)b * VAL + ar0)      * DD + ca0 * 8;
    const _Float16* ksrow1 = ksH + ((size_t)b * VAL + 64 + ar0) * DD + ca0 * 8;
    const _Float16* qrow_g = qH  + (size_t)bq * DD + ca0 * 8;   // L1-broadcast row
    const int aoff0 = tid * 8;            // chunk*8 f16 == row*BK + slot*8
    const int aoff1 = (512 + tid) * 8;

    // ---- B staging: 4 asyncs/thread; async j covers chunks j*512 + tid ----
    const _Float16* gB[4];
    int ldsBoff[4];                       // f16 units, wave-uniform + lane*16B implicit
    #pragma unroll
    for (int j = 0; j < 4; ++j) {
        int chunk = j * 512 + tid;
        int row   = chunk >> 3;           // 0..255
        int c     = ((chunk & 7) - (row & 7)) & 7;
        gB[j] = W1T + (size_t)(gy * 256 + row) * DD + c * 8;
        ldsBoff[j] = (j * 512 + wid * 64) * 8;   // wave-uniform chunk base * 8 f16
    }

    // ---- fragment offsets (f16 units); sub-step 1 = offset XOR 32 (slot+4 mod 8) ----
    int faoff[4], fboff[4];
    #pragma unroll
    for (int mt = 0; mt < 4; ++mt) {
        int row = wm * 64 + mt * 16 + lr;
        faoff[mt] = row * BK + (((quad + row) & 7) << 3);
    }
    #pragma unroll
    for (int nt = 0; nt < 4; ++nt) {
        int row = wn * 64 + nt * 16 + lr;
        fboff[nt] = row * BK + (((quad + row) & 7) << 3);
    }

    // ---- prologue: prefetch A-inputs for step 0 ----
    f16x8 kv0 = *(const f16x8*)(ksrow0);
    f16x8 kv1 = *(const f16x8*)(ksrow1);
    f16x8 qv  = *(const f16x8*)(qrow_g);

    for (int i = 0; i < 8; ++i) {
        const int kk = i * BK;
        // ---- B: 4 async global->LDS for this step
        #pragma unroll
        for (int j = 0; j < 4; ++j)
            async_copy16(gB[j] + kk, &Bh[ldsBoff[j]]);
        // ---- A: stage from prefetched registers (pure VALU + ds_write)
        *(f16x8*)&Ah[aoff0] = kv0 * qv;   // v_pk_mul_f16 x4
        *(f16x8*)&Ah[aoff1] = kv1 * qv;
        __syncthreads();                  // barrier1: staging visible (vmcnt drain)

        // ---- prefetch A-inputs for step i+1; lands under the MFMA phase
        if (i < 7) {
            kv0 = *(const f16x8*)(ksrow0 + kk + BK);
            kv1 = *(const f16x8*)(ksrow1 + kk + BK);
            qv  = *(const f16x8*)(qrow_g + kk + BK);
        }
        // ---- MFMA: two K=32 sub-steps; sub-step toggles slot by XOR 32 f16
        #pragma unroll
        for (int sub = 0; sub < 2; ++sub) {
            const int sx = sub << 5;      // 0 or 32 f16
            f16x8 fa[4];
            #pragma unroll
            for (int mt = 0; mt < 4; ++mt)
                fa[mt] = *(const f16x8*)&Ah[faoff[mt] ^ sx];
            #pragma unroll
            for (int nt = 0; nt < 4; ++nt) {
                f16x8 fb = *(const f16x8*)&Bh[fboff[nt] ^ sx];
                #pragma unroll
                for (int mt = 0; mt < 4; ++mt)
                    acc[mt][nt] = __builtin_amdgcn_mfma_f32_16x16x32_f16(fa[mt], fb, acc[mt][nt], 0, 0, 0);
            }
        }
        __syncthreads();                  // barrier2: frag reads done, LDS reusable
    }

    // ---- fused epilogue: C/D layout col=lr (e), row=quad*4+reg (v)
    float b1v[4], w2v[4];
    #pragma unroll
    for (int nt = 0; nt < 4; ++nt) {
        int col = gy*256 + wn*64 + nt*16 + lr;
        b1v[nt] = b1[col];
        w2v[nt] = W2[col];
    }
    float msum[4] = {0.f, 0.f, 0.f, 0.f};
    #pragma unroll
    for (int mt = 0; mt < 4; ++mt) {
        #pragma unroll
        for (int reg = 0; reg < 4; ++reg) {
            int v = wm*64 + mt*16 + quad*4 + reg;
            int masked = sgmask[b * VAL + v];
            float sacc = 0.f;
            #pragma unroll
            for (int nt = 0; nt < 4; ++nt) {
                float h = acc[mt][nt][reg] + b1v[nt];
                h = fmaxf(h, 0.f);
                sacc += h * w2v[nt];
                if (!masked) msum[nt] += h;
            }
            sacc += __shfl_xor(sacc, 1);
            sacc += __shfl_xor(sacc, 2);
            sacc += __shfl_xor(sacc, 4);
            sacc += __shfl_xor(sacc, 8);
            if (lr == 0) sred[wn][v] = sacc;
        }
    }
    #pragma unroll
    for (int nt = 0; nt < 4; ++nt) {
        float m = msum[nt];
        m += __shfl_xor(m, 16);
        m += __shfl_xor(m, 32);
        if (lane < 16) msumLDS[wm][wn*64 + nt*16 + lr] = m;
    }
    __syncthreads();
    if (tid < 128) {
        s_part[((size_t)bq * 2 + gy) * VAL + tid] =
            sred[0][tid] + sred[1][tid] + sred[2][tid] + sred[3][tid];
    } else if (tid >= 256) {
        int c = tid - 256;
        meansum[(size_t)bq * DD + gy*256 + c] = msumLDS[0][c] + msumLDS[1][c];
    }
}

// ---------------- final v2: single-sync. All B-operand staging (WseT, vsT) is
// input-independent -> issued at the top, in flight under the softmax/mean phase.
// One __syncthreads, then 16+4 MFMAs (gate chain split even/odd), epilogue.
// grid (16 q-tiles of 32, 16 d-tiles of 32), 256 thr = 4 waves (2m x 2n).
#define MPAD 514   // 32-row stride (f16): 257 dwords == 1 mod 32 -> conflict-free
#define WPAD 130   // 128-col row stride: 65 dwords == 1 mod 32
__global__ __launch_bounds__(256) void final_kernel(
    const float* __restrict__ s_part,     // [BQ][2][VAL]
    const float* __restrict__ msum,       // [BQ][DD]
    const int*   __restrict__ sgmask,
    const _Float16* __restrict__ WseT,    // [d][e] fp16
    const _Float16* __restrict__ vsT,     // [b][d][v] fp16
    const float* __restrict__ bse,
    const float* __restrict__ b2,
    float* __restrict__ out)              // [BQ][DD]
{
    __shared__ _Float16 meanLDS[32 * MPAD];   // 32.9 KB  A of gate GEMM (all 512 e)
    __shared__ _Float16 BW[32 * MPAD];        // 32.9 KB  B of gate GEMM (WseT rows, 512 e)
    __shared__ _Float16 wLDS[32 * WPAD];      //  8.3 KB  A of out GEMM
    __shared__ _Float16 BV[32 * WPAD];        //  8.3 KB  B of out GEMM (vsT rows)

    const int tid  = threadIdx.x;
    const int q0   = blockIdx.x * 32;
    const int d0   = blockIdx.y * 32;
    const int b    = q0 >> 7;                 // whole q-tile within one batch
    const int lane = tid & 63;
    const int wid  = tid >> 6;                // 0..3
    const int wm   = wid >> 1, wn = wid & 1;  // 2m x 2n of 16x16
    const int quad = lane >> 4;
    const int lr   = lane & 15;
    const int r    = tid >> 3;                // 0..31 (row for staging/softmax)
    const int sl   = tid & 7;                 // 0..7  (segment)

    // ---- stage B operands FIRST (independent of s_part/msum; loads overlap phase A)
    {
        const _Float16* wrow = WseT + (size_t)(d0 + r) * DD + sl*16;
        #pragma unroll
        for (int cc = 0; cc < 4; ++cc) {
            f16x8 bw0 = *(const f16x8*)(wrow + cc*128);
            f16x8 bw1 = *(const f16x8*)(wrow + cc*128 + 8);
            *(f16x8*)&BW[r * MPAD + cc*128 + sl*16]     = bw0;
            *(f16x8*)&BW[r * MPAD + cc*128 + sl*16 + 8] = bw1;
        }
        const _Float16* vrow = vsT + ((size_t)b * DD + d0 + r) * VAL + sl*16;
        f16x8 bv0 = *(const f16x8*)(vrow);
        f16x8 bv1 = *(const f16x8*)(vrow + 8);
        *(f16x8*)&BV[r * WPAD + sl*16]     = bv0;
        *(f16x8*)&BV[r * WPAD + sl*16 + 8] = bv1;
    }

    // ---- phase A: softmax over v (8 lanes/row) + mean (fold 1/denom) ----
    const float b2v = b2[0];
    const int   bq  = q0 + r;
    const float* sp = s_part + (size_t)bq * 2 * VAL;
    float vals[16];
    int   msk[16];
    float smax = -3.4e38f;
    #pragma unroll
    for (int i4 = 0; i4 < 4; ++i4) {
        f32x4 s0 = *(const f32x4*)(sp + sl*16 + i4*4);
        f32x4 s1 = *(const f32x4*)(sp + VAL + sl*16 + i4*4);
        #pragma unroll
        for (int j = 0; j < 4; ++j) {
            int idx = i4*4 + j;
            int v   = sl*16 + idx;
            float s = fmaxf(s0[j] + s1[j] + b2v, 0.f);
            int m   = sgmask[b * VAL + v];
            msk[idx] = m;
            if (m) s = -1e9f;
            vals[idx] = s;
            smax = fmaxf(smax, s);
        }
    }
    smax = fmaxf(smax, __shfl_xor(smax, 1));
    smax = fmaxf(smax, __shfl_xor(smax, 2));
    smax = fmaxf(smax, __shfl_xor(smax, 4));
    float sume = 0.f, cnt = 0.f;
    #pragma unroll
    for (int i = 0; i < 16; ++i) {
        vals[i] = __expf(vals[i] - smax);
        sume += vals[i];
        cnt  += msk[i] ? 0.f : 1.f;
    }
    sume += __shfl_xor(sume, 1);  cnt += __shfl_xor(cnt, 1);
    sume += __shfl_xor(sume, 2);  cnt += __shfl_xor(cnt, 2);
    sume += __shfl_xor(sume, 4);  cnt += __shfl_xor(cnt, 4);
    const float invse = 1.f / sume;
    const float invd  = 1.f / cnt;
    f16x8 wv0, wv1;
    #pragma unroll
    for (int i = 0; i < 8; ++i) {
        wv0[i] = (_Float16)(vals[i]     * invse);
        wv1[i] = (_Float16)(vals[i + 8] * invse);
    }
    *(f16x8*)&wLDS[r * WPAD + sl*16]     = wv0;
    *(f16x8*)&wLDS[r * WPAD + sl*16 + 8] = wv1;
    // mean: 64 e per thread, coalesced 256B/row-group
    const float* mrow = msum + (size_t)bq * DD;
    #pragma unroll
    for (int i = 0; i < 8; ++i) {
        int e = i*64 + sl*8;
        f32x4 m0 = *(const f32x4*)(mrow + e);
        f32x4 m1 = *(const f32x4*)(mrow + e + 4);
        f16x8 mh;
        #pragma unroll
        for (int c = 0; c < 4; ++c) {
            mh[c]     = (_Float16)(m0[c] * invd);
            mh[c + 4] = (_Float16)(m1[c] * invd);
        }
        *(f16x8*)&meanLDS[r * MPAD + e] = mh;
    }

    __syncthreads();   // the ONE barrier: all staging + phase-A writes visible

    // ---- phase B: gate GEMM (K=512), dep chain split even/odd ----
    f32x4 accg0 = (f32x4){0.f, 0.f, 0.f, 0.f};
    f32x4 accg1 = (f32x4){0.f, 0.f, 0.f, 0.f};
    const int a_off = (wm*16 + lr) * MPAD + quad*8;
    const int bg_off = (wn*16 + lr) * MPAD + quad*8;
    #pragma unroll
    for (int cc = 0; cc < 4; ++cc) {
        #pragma unroll
        for (int ks = 0; ks < 4; ++ks) {
            f16x8 fa = *(const f16x8*)&meanLDS[a_off + cc*128 + ks*32];
            f16x8 fb = *(const f16x8*)&BW[bg_off + cc*128 + ks*32];
            if (((cc*4 + ks) & 1) == 0)
                accg0 = __builtin_amdgcn_mfma_f32_16x16x32_f16(fa, fb, accg0, 0, 0, 0);
            else
                accg1 = __builtin_amdgcn_mfma_f32_16x16x32_f16(fa, fb, accg1, 0, 0, 0);
        }
    }

    // ---- phase C: out GEMM (K=128) ----
    f32x4 acco = (f32x4){0.f, 0.f, 0.f, 0.f};
    const int w_off = (wm*16 + lr) * WPAD + quad*8;
    const int bv_off = (wn*16 + lr) * WPAD + quad*8;
    #pragma unroll
    for (int ks = 0; ks < 4; ++ks) {
        f16x8 fa = *(const f16x8*)&wLDS[w_off + ks*32];
        f16x8 fb = *(const f16x8*)&BV[bv_off + ks*32];
        acco = __builtin_amdgcn_mfma_f32_16x16x32_f16(fa, fb, acco, 0, 0, 0);
    }

    // ---- phase D: epilogue. C/D: col=lr (d), row=quad*4+reg (q) ----
    const int d = d0 + wn*16 + lr;
    const float bsev = bse[d];
    #pragma unroll
    for (int reg = 0; reg < 4; ++reg) {
        int q = q0 + wm*16 + quad*4 + reg;
        float g = fmaxf(accg0[reg] + accg1[reg] + bsev, 0.f);
        g = 1.f / (1.f + __expf(-g));
        out[(size_t)q * DD + d] = g * acco[reg];
    }
}

extern "C" void kernel_launch(void* const* d_in, const int* in_sizes, int n_in,
                              void* d_out, int out_size, void* d_ws, size_t ws_size,
                              hipStream_t stream) {
    (void)in_sizes; (void)n_in; (void)out_size; (void)ws_size;
    const float* qs1 = (const float*)d_in[0];
    const float* ks  = (const float*)d_in[2];
    const float* vs  = (const float*)d_in[3];
    const int*   sg  = (const int*)d_in[4];
    const float* W1  = (const float*)d_in[5];
    const float* b1  = (const float*)d_in[6];
    const float* Wse = (const float*)d_in[7];
    const float* bse = (const float*)d_in[8];
    const float* W2  = (const float*)d_in[9];
    const float* b2  = (const float*)d_in[10];
    float* out = (float*)d_out;

    char* ws = (char*)d_ws;
    _Float16* W1T    = (_Float16*)(ws);                        // 512 KB
    _Float16* WseT   = (_Float16*)(ws + (512 << 10));          // 512 KB
    _Float16* vsT    = (_Float16*)(ws + (1 << 20));            // 512 KB
    float*    s_part = (float*)(ws + (1536 << 10));            // 512 KB
    float*    msum   = (float*)(ws + (2 << 20));               // 1 MB
    _Float16* qH     = (_Float16*)(ws + (3 << 20));            // 512 KB
    _Float16* ksH    = (_Float16*)(ws + (3 << 20) + (512 << 10)); // 512 KB

    prep_kernel<<<dim3(16, 52), 256, 0, stream>>>(W1, W1T, Wse, WseT, vs, vsT,
                                                  qs1, qH, ks, ksH);
    gemm_h_kernel<<<dim3(BQ, 2), 512, 0, stream>>>(qH, ksH, sg, W1T, b1, W2, s_part, msum);
    final_kernel<<<dim3(16, 16), 256, 0, stream>>>(s_part, msum, sg, WseT, vsT, bse, b2, out);
}

// Round 6
// 124.266 us; speedup vs baseline: 2.5951x; 1.0143x over previous
//
#include <hip/hip_runtime.h>
#include <stdint.h>
#include <stddef.h>

#define BDIM 4
#define QUE  128
#define VAL  128
#define DD   512
#define BQ   (BDIM*QUE)
#define BK   64
// gemm LDS: 8 slots of 8 f16 (16B) per row; true kseg c stored at slot (c + (r&7)) & 7

typedef float    f32x4 __attribute__((ext_vector_type(4)));
typedef _Float16 f16x8 __attribute__((ext_vector_type(8)));
typedef _Float16 f16x4 __attribute__((ext_vector_type(4)));

typedef const __attribute__((address_space(1))) void* gas_ptr;
typedef __attribute__((address_space(3))) void*       las_ptr;

__device__ __forceinline__ void async_copy16(const void* g, void* l) {
    __builtin_amdgcn_global_load_lds((gas_ptr)g, (las_ptr)l, 16, 0, 0);
}

// ---------------- prep v2: uniform 1-tile jobs, balanced. grid (16, 52).
//  gy  0..15 : W1  32x32 transpose tile  -> W1T[e][d]
//  gy 16..31 : Wse 32x32 transpose tile  -> WseT[d][e]
//  gy 32..47 : vs  32x32 transpose tile  -> vsT[b][d][v]   (bb=(gy-32)>>2, vt=(gy-32)&3)
//  gy 48..51 : flat f32->f16 casts: 48,49 qs1->qH halves; 50,51 ks->ksH halves
__global__ __launch_bounds__(256) void prep_kernel(const float* __restrict__ W1,
                                                   _Float16* __restrict__ W1T,
                                                   const float* __restrict__ Wse,
                                                   _Float16* __restrict__ WseT,
                                                   const float* __restrict__ vs,
                                                   _Float16* __restrict__ vsT,
                                                   const float* __restrict__ qs1,
                                                   _Float16* __restrict__ qH,
                                                   const float* __restrict__ ks,
                                                   _Float16* __restrict__ ksH) {
    const int gx = blockIdx.x, gy = blockIdx.y;
    if (gy >= 48) {
        const float* src = (gy < 50) ? qs1 : ks;
        _Float16*    dst = (gy < 50) ? qH  : ksH;
        size_t base = ((size_t)(gy & 1) * 16 + gx) * 8192 + threadIdx.x * 4;
        #pragma unroll
        for (int i = 0; i < 8; ++i) {
            f32x4 w = *(const f32x4*)(src + base + (size_t)i * 1024);
            f16x4 h;
            h[0] = (_Float16)w[0]; h[1] = (_Float16)w[1];
            h[2] = (_Float16)w[2]; h[3] = (_Float16)w[3];
            *(f16x4*)(dst + base + (size_t)i * 1024) = h;
        }
        return;
    }
    __shared__ float tile[32][33];
    const int tx = threadIdx.x & 31;
    const int ty = threadIdx.x >> 5;      // 0..7
    const float* src;
    _Float16*    dst;
    int a0, b0, dstride;
    if (gy < 32) {
        src = (gy < 16) ? W1  : Wse;
        dst = (gy < 16) ? W1T : WseT;
        a0 = gx * 32;                     // source-row tile (d)
        b0 = (gy & 15) * 32;              // source-col tile (e)
        dstride = DD;
    } else {
        const int j  = gy - 32;
        const int bb = j >> 2;            // batch
        const int vt = j & 3;             // v subtile
        src = vs  + (size_t)bb * VAL * DD;
        dst = vsT + (size_t)bb * DD * VAL;
        a0 = vt * 32;                     // source-row tile (v)
        b0 = gx * 32;                     // source-col tile (d)
        dstride = VAL;
    }
    #pragma unroll
    for (int r = 0; r < 4; ++r)
        tile[ty + r*8][tx] = src[(size_t)(a0 + ty + r*8) * DD + b0 + tx];
    __syncthreads();
    #pragma unroll
    for (int r = 0; r < 4; ++r) {
        int el = ty + r*8;
        dst[(size_t)(b0 + el) * dstride + a0 + tx] = (_Float16)tile[tx][el];
    }
}

// ---------------- fused GEMM: h=relu((q*k)@W1+b1); emit s-partials + masked colsums
// grid (BQ, 2); block 512 = 8 waves as 2m x 4n of 64x64. Tile 128 rows x 256 e-cols.
// r5 structure + Bh DOUBLE-BUFFER in previously-unused LDS (occupancy is VGPR-capped
// at 2 blocks/CU: 64 arch + 64 acc = 128/wave -> 4 waves/SIMD; LDS 81920x2 = 160 KiB
// exact fit, so residency is unchanged). B(i+1) asyncs issue right after barrier1 of
// step i -> a full step of flight; barrier1's vmcnt(0) drains step-old loads (~free).
// barrier2 is a RAW s_barrier (frag ds_reads are already retired by the compiler's
// per-MFMA lgkm waits), so fresh kv prefetches are NOT drained there.
__global__ __launch_bounds__(512, 4) void gemm_h_kernel(
    const _Float16* __restrict__ qH,    // [BQ][DD] fp16
    const _Float16* __restrict__ ksH,   // [B][VAL][DD] fp16
    const int*   __restrict__ sgmask,
    const _Float16* __restrict__ W1T,   // [e][d] fp16
    const float* __restrict__ b1,
    const float* __restrict__ W2,
    float* __restrict__ s_part,         // [BQ][2][VAL]
    float* __restrict__ meansum)        // [BQ][DD]
{
    __shared__ _Float16 Ah[128 * BK];       // x tile   [v][k]  16 KB
    __shared__ _Float16 Bh[2][256 * BK];    // W1T tile [e][k]  32 KB x2 (dbuf)
    // epilogue scratch aliases Ah (only used after the K loop):
    float (*sred)[VAL]    = (float(*)[VAL])(&Ah[0]);      // 2048 B
    float (*msumLDS)[256] = (float(*)[256])(&Ah[1024]);   // 2048 B (f16 idx 1024 = byte 2048)

    const int tid  = threadIdx.x;
    const int bq   = blockIdx.x;
    const int gy   = blockIdx.y;          // e-half: cols [gy*256, gy*256+256)
    const int b    = bq >> 7;
    const int lane = tid & 63;
    const int wid  = tid >> 6;            // 0..7
    const int wm   = wid >> 2;            // 0..1 (rows wm*64)
    const int wn   = wid & 3;             // 0..3 (cols wn*64)
    const int quad = lane >> 4;
    const int lr   = lane & 15;

    f32x4 acc[4][4];
    #pragma unroll
    for (int i = 0; i < 4; ++i)
        #pragma unroll
        for (int j = 0; j < 4; ++j) acc[i][j] = (f32x4){0.f, 0.f, 0.f, 0.f};

    // ---- A staging: 2 chunks/thread (chunk = tid, tid+512); chunk -> row=c>>3, slot=c&7
    const int ar0 = tid >> 3;             // chunk tid   -> row 0..63
    const int slt = tid & 7;
    const int ca0 = (slt - (ar0 & 7)) & 7;   // true kseg; rows ar0 and ar0+64 share it
    const _Float16* ksrow0 = ksH + ((size_t)b * VAL + ar0)      * DD + ca0 * 8;
    const _Float16* ksrow1 = ksH + ((size_t)b * VAL + 64 + ar0) * DD + ca0 * 8;
    const _Float16* qrow_g = qH  + (size_t)bq * DD + ca0 * 8;   // L1-broadcast row
    const int aoff0 = tid * 8;            // chunk*8 f16 == row*BK + slot*8
    const int aoff1 = (512 + tid) * 8;

    // ---- B staging: 4 asyncs/thread; async j covers chunks j*512 + tid ----
    const _Float16* gB[4];
    int ldsBoff[4];                       // f16 units, wave-uniform + lane*16B implicit
    #pragma unroll
    for (int j = 0; j < 4; ++j) {
        int chunk = j * 512 + tid;
        int row   = chunk >> 3;           // 0..255
        int c     = ((chunk & 7) - (row & 7)) & 7;
        gB[j] = W1T + (size_t)(gy * 256 + row) * DD + c * 8;
        ldsBoff[j] = (j * 512 + wid * 64) * 8;   // wave-uniform chunk base * 8 f16
    }

    // ---- fragment offsets (f16 units); sub-step 1 = offset XOR 32 (slot+4 mod 8) ----
    int faoff[4], fboff[4];
    #pragma unroll
    for (int mt = 0; mt < 4; ++mt) {
        int row = wm * 64 + mt * 16 + lr;
        faoff[mt] = row * BK + (((quad + row) & 7) << 3);
    }
    #pragma unroll
    for (int nt = 0; nt < 4; ++nt) {
        int row = wn * 64 + nt * 16 + lr;
        fboff[nt] = row * BK + (((quad + row) & 7) << 3);
    }

    // ---- prologue: B(0) asyncs -> Bh[0]; then A-input prefetch for step 0 ----
    #pragma unroll
    for (int j = 0; j < 4; ++j)
        async_copy16(gB[j], &Bh[0][ldsBoff[j]]);
    f16x8 kv0 = *(const f16x8*)(ksrow0);
    f16x8 kv1 = *(const f16x8*)(ksrow1);
    f16x8 qv  = *(const f16x8*)(qrow_g);

    int p = 0;
    for (int i = 0; i < 8; ++i) {
        const int kk = i * BK;
        // ---- A: stage from prefetched registers (pure VALU + ds_write)
        *(f16x8*)&Ah[aoff0] = kv0 * qv;   // v_pk_mul_f16 x4
        *(f16x8*)&Ah[aoff1] = kv1 * qv;
        __syncthreads();                  // barrier1: vmcnt(0) drains B(i) (step-old, ~free)

        if (i < 7) {
            // kv/qv(i+1) FIRST (older in FIFO than the asyncs below -> their consumer
            // waits vmcnt(4), keeping B(i+1) in flight through the next A-stage)
            kv0 = *(const f16x8*)(ksrow0 + kk + BK);
            kv1 = *(const f16x8*)(ksrow1 + kk + BK);
            qv  = *(const f16x8*)(qrow_g + kk + BK);
            // B(i+1) asyncs -> Bh[p^1]; flight = entire MFMA phase + next A-stage
            #pragma unroll
            for (int j = 0; j < 4; ++j)
                async_copy16(gB[j] + kk + BK, &Bh[p ^ 1][ldsBoff[j]]);
        }
        // ---- MFMA: two K=32 sub-steps on Ah / Bh[p]
        const _Float16* Bb = &Bh[p][0];
        #pragma unroll
        for (int sub = 0; sub < 2; ++sub) {
            const int sx = sub << 5;      // 0 or 32 f16
            f16x8 fa[4];
            #pragma unroll
            for (int mt = 0; mt < 4; ++mt)
                fa[mt] = *(const f16x8*)&Ah[faoff[mt] ^ sx];
            #pragma unroll
            for (int nt = 0; nt < 4; ++nt) {
                f16x8 fb = *(const f16x8*)&Bb[fboff[nt] ^ sx];
                #pragma unroll
                for (int mt = 0; mt < 4; ++mt)
                    acc[mt][nt] = __builtin_amdgcn_mfma_f32_16x16x32_f16(fa[mt], fb, acc[mt][nt], 0, 0, 0);
            }
        }
        // barrier2: RAW s_barrier, no counter drain. Safe: this wave's frag ds_reads
        // retired before their consuming MFMAs (compiler lgkm waits); Bh[p] is not
        // rewritten until after the NEXT barrier1; Ah rewrite happens post-barrier.
        asm volatile("s_barrier" ::: "memory");
        p ^= 1;
    }

    // ---- fused epilogue: C/D layout col=lr (e), row=quad*4+reg (v)
    float b1v[4], w2v[4];
    #pragma unroll
    for (int nt = 0; nt < 4; ++nt) {
        int col = gy*256 + wn*64 + nt*16 + lr;
        b1v[nt] = b1[col];
        w2v[nt] = W2[col];
    }
    float msum[4] = {0.f, 0.f, 0.f, 0.f};
    #pragma unroll
    for (int mt = 0; mt < 4; ++mt) {
        #pragma unroll
        for (int reg = 0; reg < 4; ++reg) {
            int v = wm*64 + mt*16 + quad*4 + reg;
            int masked = sgmask[b * VAL + v];
            float sacc = 0.f;
            #pragma unroll
            for (int nt = 0; nt < 4; ++nt) {
                float h = acc[mt][nt][reg] + b1v[nt];
                h = fmaxf(h, 0.f);
                sacc += h * w2v[nt];
                if (!masked) msum[nt] += h;
            }
            sacc += __shfl_xor(sacc, 1);
            sacc += __shfl_xor(sacc, 2);
            sacc += __shfl_xor(sacc, 4);
            sacc += __shfl_xor(sacc, 8);
            if (lr == 0) sred[wn][v] = sacc;
        }
    }
    #pragma unroll
    for (int nt = 0; nt < 4; ++nt) {
        float m = msum[nt];
        m += __shfl_xor(m, 16);
        m += __shfl_xor(m, 32);
        if (lane < 16) msumLDS[wm][wn*64 + nt*16 + lr] = m;
    }
    __syncthreads();
    if (tid < 128) {
        s_part[((size_t)bq * 2 + gy) * VAL + tid] =
            sred[0][tid] + sred[1][tid] + sred[2][tid] + sred[3][tid];
    } else if (tid >= 256) {
        int c = tid - 256;
        meansum[(size_t)bq * DD + gy*256 + c] = msumLDS[0][c] + msumLDS[1][c];
    }
}

// ---------------- final v2: single-sync. All B-operand staging (WseT, vsT) is
// input-independent -> issued at the top, in flight under the softmax/mean phase.
// One __syncthreads, then 16+4 MFMAs (gate chain split even/odd), epilogue.
// grid (16 q-tiles of 32, 16 d-tiles of 32), 256 thr = 4 waves (2m x 2n).
#define MPAD 514   // 32-row stride (f16): 257 dwords == 1 mod 32 -> conflict-free
#define WPAD 130   // 128-col row stride: 65 dwords == 1 mod 32
__global__ __launch_bounds__(256) void final_kernel(
    const float* __restrict__ s_part,     // [BQ][2][VAL]
    const float* __restrict__ msum,       // [BQ][DD]
    const int*   __restrict__ sgmask,
    const _Float16* __restrict__ WseT,    // [d][e] fp16
    const _Float16* __restrict__ vsT,     // [b][d][v] fp16
    const float* __restrict__ bse,
    const float* __restrict__ b2,
    float* __restrict__ out)              // [BQ][DD]
{
    __shared__ _Float16 meanLDS[32 * MPAD];   // 32.9 KB  A of gate GEMM (all 512 e)
    __shared__ _Float16 BW[32 * MPAD];        // 32.9 KB  B of gate GEMM (WseT rows, 512 e)
    __shared__ _Float16 wLDS[32 * WPAD];      //  8.3 KB  A of out GEMM
    __shared__ _Float16 BV[32 * WPAD];        //  8.3 KB  B of out GEMM (vsT rows)

    const int tid  = threadIdx.x;
    const int q0   = blockIdx.x * 32;
    const int d0   = blockIdx.y * 32;
    const int b    = q0 >> 7;                 // whole q-tile within one batch
    const int lane = tid & 63;
    const int wid  = tid >> 6;                // 0..3
    const int wm   = wid >> 1, wn = wid & 1;  // 2m x 2n of 16x16
    const int quad = lane >> 4;
    const int lr   = lane & 15;
    const int r    = tid >> 3;                // 0..31 (row for staging/softmax)
    const int sl   = tid & 7;                 // 0..7  (segment)

    // ---- stage B operands FIRST (independent of s_part/msum; loads overlap phase A)
    {
        const _Float16* wrow = WseT + (size_t)(d0 + r) * DD + sl*16;
        #pragma unroll
        for (int cc = 0; cc < 4; ++cc) {
            f16x8 bw0 = *(const f16x8*)(wrow + cc*128);
            f16x8 bw1 = *(const f16x8*)(wrow + cc*128 + 8);
            *(f16x8*)&BW[r * MPAD + cc*128 + sl*16]     = bw0;
            *(f16x8*)&BW[r * MPAD + cc*128 + sl*16 + 8] = bw1;
        }
        const _Float16* vrow = vsT + ((size_t)b * DD + d0 + r) * VAL + sl*16;
        f16x8 bv0 = *(const f16x8*)(vrow);
        f16x8 bv1 = *(const f16x8*)(vrow + 8);
        *(f16x8*)&BV[r * WPAD + sl*16]     = bv0;
        *(f16x8*)&BV[r * WPAD + sl*16 + 8] = bv1;
    }

    // ---- phase A: softmax over v (8 lanes/row) + mean (fold 1/denom) ----
    const float b2v = b2[0];
    const int   bq  = q0 + r;
    const float* sp = s_part + (size_t)bq * 2 * VAL;
    float vals[16];
    int   msk[16];
    float smax = -3.4e38f;
    #pragma unroll
    for (int i4 = 0; i4 < 4; ++i4) {
        f32x4 s0 = *(const f32x4*)(sp + sl*16 + i4*4);
        f32x4 s1 = *(const f32x4*)(sp + VAL + sl*16 + i4*4);
        #pragma unroll
        for (int j = 0; j < 4; ++j) {
            int idx = i4*4 + j;
            int v   = sl*16 + idx;
            float s = fmaxf(s0[j] + s1[j] + b2v, 0.f);
            int m   = sgmask[b * VAL + v];
            msk[idx] = m;
            if (m) s = -1e9f;
            vals[idx] = s;
            smax = fmaxf(smax, s);
        }
    }
    smax = fmaxf(smax, __shfl_xor(smax, 1));
    smax = fmaxf(smax, __shfl_xor(smax, 2));
    smax = fmaxf(smax, __shfl_xor(smax, 4));
    float sume = 0.f, cnt = 0.f;
    #pragma unroll
    for (int i = 0; i < 16; ++i) {
        vals[i] = __expf(vals[i] - smax);
        sume += vals[i];
        cnt  += msk[i] ? 0.f : 1.f;
    }
    sume += __shfl_xor(sume, 1);  cnt += __shfl_xor(cnt, 1);
    sume += __shfl_xor(sume, 2);  cnt += __shfl_xor(cnt, 2);
    sume += __shfl_xor(sume, 4);  cnt += __shfl_xor(cnt, 4);
    const float invse = 1.f / sume;
    const float invd  = 1.f / cnt;
    f16x8 wv0, wv1;
    #pragma unroll
    for (int i = 0; i < 8; ++i) {
        wv0[i] = (_Float16)(vals[i]     * invse);
        wv1[i] = (_Float16)(vals[i + 8] * invse);
    }
    *(f16x8*)&wLDS[r * WPAD + sl*16]     = wv0;
    *(f16x8*)&wLDS[r * WPAD + sl*16 + 8] = wv1;
    // mean: 64 e per thread, coalesced 256B/row-group
    const float* mrow = msum + (size_t)bq * DD;
    #pragma unroll
    for (int i = 0; i < 8; ++i) {
        int e = i*64 + sl*8;
        f32x4 m0 = *(const f32x4*)(mrow + e);
        f32x4 m1 = *(const f32x4*)(mrow + e + 4);
        f16x8 mh;
        #pragma unroll
        for (int c = 0; c < 4; ++c) {
            mh[c]     = (_Float16)(m0[c] * invd);
            mh[c + 4] = (_Float16)(m1[c] * invd);
        }
        *(f16x8*)&meanLDS[r * MPAD + e] = mh;
    }

    __syncthreads();   // the ONE barrier: all staging + phase-A writes visible

    // ---- phase B: gate GEMM (K=512), dep chain split even/odd ----
    f32x4 accg0 = (f32x4){0.f, 0.f, 0.f, 0.f};
    f32x4 accg1 = (f32x4){0.f, 0.f, 0.f, 0.f};
    const int a_off = (wm*16 + lr) * MPAD + quad*8;
    const int bg_off = (wn*16 + lr) * MPAD + quad*8;
    #pragma unroll
    for (int cc = 0; cc < 4; ++cc) {
        #pragma unroll
        for (int ks = 0; ks < 4; ++ks) {
            f16x8 fa = *(const f16x8*)&meanLDS[a_off + cc*128 + ks*32];
            f16x8 fb = *(const f16x8*)&BW[bg_off + cc*128 + ks*32];
            if (((cc*4 + ks) & 1) == 0)
                accg0 = __builtin_amdgcn_mfma_f32_16x16x32_f16(fa, fb, accg0, 0, 0, 0);
            else
                accg1 = __builtin_amdgcn_mfma_f32_16x16x32_f16(fa, fb, accg1, 0, 0, 0);
        }
    }

    // ---- phase C: out GEMM (K=128) ----
    f32x4 acco = (f32x4){0.f, 0.f, 0.f, 0.f};
    const int w_off = (wm*16 + lr) * WPAD + quad*8;
    const int bv_off = (wn*16 + lr) * WPAD + quad*8;
    #pragma unroll
    for (int ks = 0; ks < 4; ++ks) {
        f16x8 fa = *(const f16x8*)&wLDS[w_off + ks*32];
        f16x8 fb = *(const f16x8*)&BV[bv_off + ks*32];
        acco = __builtin_amdgcn_mfma_f32_16x16x32_f16(fa, fb, acco, 0, 0, 0);
    }

    // ---- phase D: epilogue. C/D: col=lr (d), row=quad*4+reg (q) ----
    const int d = d0 + wn*16 + lr;
    const float bsev = bse[d];
    #pragma unroll
    for (int reg = 0; reg < 4; ++reg) {
        int q = q0 + wm*16 + quad*4 + reg;
        float g = fmaxf(accg0[reg] + accg1[reg] + bsev, 0.f);
        g = 1.f / (1.f + __expf(-g));
        out[(size_t)q * DD + d] = g * acco[reg];
    }
}

extern "C" void kernel_launch(void* const* d_in, const int* in_sizes, int n_in,
                              void* d_out, int out_size, void* d_ws, size_t ws_size,
                              hipStream_t stream) {
    (void)in_sizes; (void)n_in; (void)out_size; (void)ws_size;
    const float* qs1 = (const float*)d_in[0];
    const float* ks  = (const float*)d_in[2];
    const float* vs  = (const float*)d_in[3];
    const int*   sg  = (const int*)d_in[4];
    const float* W1  = (const float*)d_in[5];
    const float* b1  = (const float*)d_in[6];
    const float* Wse = (const float*)d_in[7];
    const float* bse = (const float*)d_in[8];
    const float* W2  = (const float*)d_in[9];
    const float* b2  = (const float*)d_in[10];
    float* out = (float*)d_out;

    char* ws = (char*)d_ws;
    _Float16* W1T    = (_Float16*)(ws);                        // 512 KB
    _Float16* WseT   = (_Float16*)(ws + (512 << 10));          // 512 KB
    _Float16* vsT    = (_Float16*)(ws + (1 << 20));            // 512 KB
    float*    s_part = (float*)(ws + (1536 << 10));            // 512 KB
    float*    msum   = (float*)(ws + (2 << 20));               // 1 MB
    _Float16* qH     = (_Float16*)(ws + (3 << 20));            // 512 KB
    _Float16* ksH    = (_Float16*)(ws + (3 << 20) + (512 << 10)); // 512 KB

    prep_kernel<<<dim3(16, 52), 256, 0, stream>>>(W1, W1T, Wse, WseT, vs, vsT,
                                                  qs1, qH, ks, ksH);
    gemm_h_kernel<<<dim3(BQ, 2), 512, 0, stream>>>(qH, ksH, sg, W1T, b1, W2, s_part, msum);
    final_kernel<<<dim3(16, 16), 256, 0, stream>>>(s_part, msum, sg, WseT, vsT, bse, b2, out);
}